// Round 7
// baseline (164.523 us; speedup 1.0000x reference)
//
#include <hip/hip_runtime.h>
#include <math.h>

#define NPIX 262144   // 512*512
#define NKER 15
#define PI_F 3.14159265358979323846f
#define HW 264        // half-plane row stride (float2): 257 used, padded to 8
#define CS 578        // wave scratch stride (float2): >= SK(511)=574
#define SK(n) ((n) + ((n) >> 3))   // skewed LDS index: <=4-way conflicts

__device__ __forceinline__ float2 cadd(float2 a, float2 b) { return make_float2(a.x + b.x, a.y + b.y); }
__device__ __forceinline__ float2 csub(float2 a, float2 b) { return make_float2(a.x - b.x, a.y - b.y); }
__device__ __forceinline__ float2 cmul(float2 a, float2 b) {
  return make_float2(a.x * b.x - a.y * b.y, a.x * b.y + a.y * b.x);
}

// per-lane FFT roots: w1 = e^{-2pi i lane/512}, wh = e^{-2pi i (lane&~7)/512}
__device__ __forceinline__ void fft_roots(int lane, float2* w1, float2* wh) {
  float s, c;
  sincosf(-2.0f * PI_F * (float)lane / 512.0f, &s, &c);
  *w1 = make_float2(c, s);
  int h = lane & ~7;
  *wh = make_float2(__shfl(c, h, 64), __shfl(s, h, 64));
}

template <bool INV>
__device__ __forceinline__ void dft8(float2 a[8]) {
  const float R = 0.70710678118654752f;
  float2 t0 = cadd(a[0], a[4]), u0 = csub(a[0], a[4]);
  float2 t1 = cadd(a[1], a[5]), u1 = csub(a[1], a[5]);
  float2 t2 = cadd(a[2], a[6]), u2 = csub(a[2], a[6]);
  float2 t3 = cadd(a[3], a[7]), u3 = csub(a[3], a[7]);
  u1 = INV ? make_float2(R * (u1.x - u1.y), R * (u1.x + u1.y))
           : make_float2(R * (u1.x + u1.y), R * (u1.y - u1.x));
  u2 = INV ? make_float2(-u2.y, u2.x) : make_float2(u2.y, -u2.x);
  u3 = INV ? make_float2(-R * (u3.x + u3.y), R * (u3.x - u3.y))
           : make_float2(R * (u3.y - u3.x), -R * (u3.x + u3.y));
  float2 e0 = cadd(t0, t2), f0 = csub(t0, t2);
  float2 e1 = cadd(t1, t3), f1 = csub(t1, t3);
  f1 = INV ? make_float2(-f1.y, f1.x) : make_float2(f1.y, -f1.x);
  float2 g0 = cadd(u0, u2), h0 = csub(u0, u2);
  float2 g1 = cadd(u1, u3), h1 = csub(u1, u3);
  h1 = INV ? make_float2(-h1.y, h1.x) : make_float2(h1.y, -h1.x);
  a[0] = cadd(e0, e1); a[4] = csub(e0, e1);
  a[2] = cadd(f0, f1); a[6] = csub(f0, f1);
  a[1] = cadd(g0, g1); a[5] = csub(g0, g1);
  a[3] = cadd(h0, h1); a[7] = csub(h0, h1);
}

// 512-pt Stockham radix-8, one wave, 8 pts/thread, a[q] = point (lane+64q).
// buf = wave-private SK-layout scratch. Twiddles via register recurrence.
template <bool INV>
__device__ __forceinline__ void fft512_r8(float2 a[8], float2* buf, int lane,
                                          float2 w1, float2 wh) {
  float2 wa = INV ? make_float2(w1.x, -w1.y) : w1;
  float2 wb = INV ? make_float2(wh.x, -wh.y) : wh;
  dft8<INV>(a);
  {
    float2 tq = wa;
    a[1] = cmul(a[1], tq);
#pragma unroll
    for (int q = 2; q < 8; ++q) { tq = cmul(tq, wa); a[q] = cmul(a[q], tq); }
  }
#pragma unroll
  for (int q = 0; q < 8; ++q) buf[9 * lane + q] = a[q];
#pragma unroll
  for (int q = 0; q < 8; ++q) a[q] = buf[SK(lane + 64 * q)];
  dft8<INV>(a);
  {
    float2 tq = wb;
    a[1] = cmul(a[1], tq);
#pragma unroll
    for (int q = 2; q < 8; ++q) { tq = cmul(tq, wb); a[q] = cmul(a[q], tq); }
  }
  int h = lane & ~7;
  int b2 = 9 * h + (lane - h);
#pragma unroll
  for (int q = 0; q < 8; ++q) buf[b2 + 9 * q] = a[q];
#pragma unroll
  for (int q = 0; q < 8; ++q) a[q] = buf[SK(lane + 64 * q)];
  dft8<INV>(a);
}

// After packed FFT Z of (rowA + i rowB): write half-plane spectra of both rows.
__device__ __forceinline__ void split_store_halfplane(float2 a[8], float2* buf, int lane,
                                                      float2* d0, float2* d1) {
#pragma unroll
  for (int q = 0; q < 8; ++q) buf[SK(lane + 64 * q)] = a[q];
#pragma unroll
  for (int q = 0; q < 4; ++q) {
    int v = lane + 64 * q;
    int mir = (512 - v) & 511;
    float2 P = a[q];
    float2 Qc = buf[SK(mir)];
    float2 Q = make_float2(Qc.x, -Qc.y);       // conj(Z[-v])
    d0[v] = make_float2(0.5f * (P.x + Q.x), 0.5f * (P.y + Q.y));
    d1[v] = make_float2(0.5f * (P.y - Q.y), -0.5f * (P.x - Q.x));
  }
  if (lane == 0) {  // v = 256
    float2 P = a[4];
    d0[256] = make_float2(P.x, 0.f);
    d1[256] = make_float2(P.y, 0.f);
  }
}

// ---- kprep: transpose Ks [p][k] -> Kt [k][p], fused block-partial k-sums ----
__global__ void kprep(const float* __restrict__ Ks, float* __restrict__ Kt,
                      float* __restrict__ partial) {
  __shared__ float wsum[4][16];
  int p = blockIdx.x * 256 + threadIdx.x;
  const float* src = Ks + (size_t)p * NKER;
  float v[NKER];
#pragma unroll
  for (int k = 0; k < NKER; ++k) v[k] = src[k];
#pragma unroll
  for (int k = 0; k < NKER; ++k) Kt[(size_t)k * NPIX + p] = v[k];
#pragma unroll
  for (int k = 0; k < NKER; ++k) {
#pragma unroll
    for (int off = 32; off > 0; off >>= 1) v[k] += __shfl_down(v[k], off, 64);
  }
  int wave = threadIdx.x >> 6;
  if ((threadIdx.x & 63) == 0) {
#pragma unroll
    for (int k = 0; k < NKER; ++k) wsum[wave][k] = v[k];
  }
  __syncthreads();
  if (threadIdx.x < NKER) {
    int k = threadIdx.x;
    partial[blockIdx.x * 16 + k] = wsum[0][k] + wsum[1][k] + wsum[2][k] + wsum[3][k];
  }
}

__global__ void ksum_final(const float* __restrict__ partial, float* __restrict__ sums) {
  __shared__ float red[256];
  int t = threadIdx.x;
  int k = t & 15, g = t >> 4;
  float acc = 0.f;
  for (int b = g; b < 1024; b += 16) acc += partial[b * 16 + k];
  red[t] = acc;
  __syncthreads();
  if (t < 16) {
    float s = 0.f;
#pragma unroll
    for (int g2 = 0; g2 < 16; ++g2) s += red[g2 * 16 + t];
    sums[t] = s;
  }
}

// ---- R2C row FFT of x: pack rows (r, r+256) -> AxH[c][row][v], v=0..256 ----
__global__ void fft_rows_x(const float* __restrict__ x, float2* __restrict__ AxH) {
  __shared__ float2 scr[4][CS];
  int t = threadIdx.x, wave = t >> 6, lane = t & 63;
  int rp = blockIdx.x * 4 + wave;   // 0..255
  int c = blockIdx.y;
  int r0 = rp, r1 = rp + 256;
  float2 w1, wh;
  fft_roots(lane, &w1, &wh);
  float2 a[8];
#pragma unroll
  for (int q = 0; q < 8; ++q) {
    int y = lane + 64 * q;
    a[q] = make_float2(x[((size_t)r0 * 512 + y) * 3 + c],
                       x[((size_t)r1 * 512 + y) * 3 + c]);
  }
  fft512_r8<false>(a, &scr[wave][0], lane, w1, wh);
  float2* d0 = AxH + ((size_t)c * 512 + r0) * HW;
  float2* d1 = AxH + ((size_t)c * 512 + r1) * HW;
  split_store_halfplane(a, &scr[wave][0], lane, d0, d1);
}

// ---- R2C row FFT of fftshift(Kt[k])/norm: pack output rows (b, b+256) ----
// fftshift: output row b sources Kt row (b+256)&511; column shift via ys.
__global__ void fft_rows_k(const float* __restrict__ Kt, const float* __restrict__ sums,
                           float2* __restrict__ AkH) {
  __shared__ float2 scr[4][CS];
  int t = threadIdx.x, wave = t >> 6, lane = t & 63;
  int rp = blockIdx.x * 4 + wave;   // 0..255 output row-pair id
  int k = blockIdx.y;
  float sc = 1.0f / (sums[k] * 262144.0f);
  const float* s0 = Kt + (size_t)k * NPIX + (size_t)(rp + 256) * 512; // -> out row rp
  const float* s1 = Kt + (size_t)k * NPIX + (size_t)rp * 512;         // -> out row rp+256
  float2 w1, wh;
  fft_roots(lane, &w1, &wh);
  float2 a[8];
#pragma unroll
  for (int q = 0; q < 8; ++q) {
    int ys = (lane + 64 * q + 256) & 511;
    a[q] = make_float2(s0[ys] * sc, s1[ys] * sc);
  }
  fft512_r8<false>(a, &scr[wave][0], lane, w1, wh);
  float2* d0 = AkH + ((size_t)k * 512 + rp) * HW;
  float2* d1 = AkH + ((size_t)k * 512 + rp + 256) * HW;
  split_store_halfplane(a, &scr[wave][0], lane, d0, d1);
}

// ---- fused column pass on the half-plane: 33 slabs of 8 columns ----
__global__ void fused_cols(float2* __restrict__ AkH, const float2* __restrict__ AxH,
                           const int* __restrict__ c0) {
  __shared__ float2 buf[8 * CS];   // 36992 B
  int t = threadIdx.x, col0 = blockIdx.x * 8, k = blockIdx.y;
  int c = t >> 6, lane = t & 63;
  float2 w1, wh;
  fft_roots(lane, &w1, &wh);
  int c0k = c0[k];
  const float2* bx = AxH + (size_t)c0k * 512 * HW;
  float2* bk = AkH + (size_t)k * 512 * HW;
#pragma unroll
  for (int u = 0; u < 8; ++u) {
    int idx = (u << 9) + t;
    int row = idx >> 3, cc = idx & 7;
    buf[cc * CS + SK(row)] = bx[(size_t)row * HW + col0 + cc];
  }
  __syncthreads();
  float2 xh[8];
#pragma unroll
  for (int q = 0; q < 8; ++q) xh[q] = buf[c * CS + SK(lane + 64 * q)];
  fft512_r8<false>(xh, &buf[c * CS], lane, w1, wh);
  __syncthreads();
#pragma unroll
  for (int u = 0; u < 8; ++u) {
    int idx = (u << 9) + t;
    int row = idx >> 3, cc = idx & 7;
    buf[cc * CS + SK(row)] = bk[(size_t)row * HW + col0 + cc];
  }
  __syncthreads();
  float2 a[8];
#pragma unroll
  for (int q = 0; q < 8; ++q) a[q] = buf[c * CS + SK(lane + 64 * q)];
  fft512_r8<false>(a, &buf[c * CS], lane, w1, wh);
#pragma unroll
  for (int q = 0; q < 8; ++q) a[q] = cmul(a[q], xh[q]);
  fft512_r8<true>(a, &buf[c * CS], lane, w1, wh);
#pragma unroll
  for (int q = 0; q < 8; ++q) buf[c * CS + SK(lane + 64 * q)] = a[q];
  __syncthreads();
#pragma unroll
  for (int u = 0; u < 8; ++u) {
    int idx = (u << 9) + t;
    int row = idx >> 3, cc = idx & 7;
    bk[(size_t)row * HW + col0 + cc] = buf[cc * CS + SK(row)];
  }
}

// ---- C2R inverse row FFT + growth + combine, 2 kernels packed per FFT ----
__global__ void irows_growth_combine(const float2* __restrict__ AkH,
                                     const float* __restrict__ m, const float* __restrict__ s,
                                     const float* __restrict__ h, const float* __restrict__ w,
                                     float* __restrict__ Hs) {
  __shared__ float2 scr[4][CS];
  __shared__ float accL[4][3][512];
  __shared__ float mk[16], isk[16], hk[16], wk[16][3];
  int t = threadIdx.x, wave = t >> 6, lane = t & 63;
  int row = blockIdx.x;
  if (t < NKER) {
    mk[t] = m[t]; isk[t] = 1.0f / s[t]; hk[t] = h[t];
    wk[t][0] = w[t * 3 + 0]; wk[t][1] = w[t * 3 + 1]; wk[t][2] = w[t * 3 + 2];
  }
  __syncthreads();
  float2 w1, wh;
  fft_roots(lane, &w1, &wh);
  float acc[3][8];
#pragma unroll
  for (int cc = 0; cc < 3; ++cc)
#pragma unroll
    for (int q = 0; q < 8; ++q) acc[cc][q] = 0.f;
  for (int si = 0; si < 2; ++si) {
    int slot = wave + 4 * si;
    int k1 = 2 * slot, k2 = 2 * slot + 1;
    bool dual = (k2 < NKER);
    const float2* p1 = AkH + ((size_t)k1 * 512 + row) * HW;
    const float2* p2 = AkH + ((size_t)(dual ? k2 : k1) * 512 + row) * HW;
    float2 a[8];
#pragma unroll
    for (int q = 0; q < 8; ++q) {
      int v = lane + 64 * q;
      if (v <= 256) {
        float2 A1 = p1[v];
        float2 A2 = dual ? p2[v] : make_float2(0.f, 0.f);
        a[q] = make_float2(A1.x - A2.y, A1.y + A2.x);          // A1 + i*A2
      } else {
        int mi = 512 - v;
        float2 A1 = p1[mi];
        float2 A2 = dual ? p2[mi] : make_float2(0.f, 0.f);
        a[q] = make_float2(A1.x + A2.y, -A1.y + A2.x);         // conj(A1) + i*conj(A2)
      }
    }
    fft512_r8<true>(a, &scr[wave][0], lane, w1, wh);
    float m1 = mk[k1], i1 = isk[k1], h1 = hk[k1];
    float w10 = wk[k1][0], w11 = wk[k1][1], w12 = wk[k1][2];
#pragma unroll
    for (int q = 0; q < 8; ++q) {
      float tt = (a[q].x - m1) * i1;
      float g = (expf(-0.5f * tt * tt) * 2.0f - 1.0f) * h1;
      acc[0][q] += g * w10; acc[1][q] += g * w11; acc[2][q] += g * w12;
    }
    if (dual) {
      float m2 = mk[k2], i2 = isk[k2], h2 = hk[k2];
      float w20 = wk[k2][0], w21 = wk[k2][1], w22 = wk[k2][2];
#pragma unroll
      for (int q = 0; q < 8; ++q) {
        float tt = (a[q].y - m2) * i2;
        float g = (expf(-0.5f * tt * tt) * 2.0f - 1.0f) * h2;
        acc[0][q] += g * w20; acc[1][q] += g * w21; acc[2][q] += g * w22;
      }
    }
  }
#pragma unroll
  for (int cc = 0; cc < 3; ++cc)
#pragma unroll
    for (int q = 0; q < 8; ++q) accL[wave][cc][lane + 64 * q] = acc[cc][q];
  __syncthreads();
#pragma unroll
  for (int cc = 0; cc < 3; ++cc) {
#pragma unroll
    for (int rep = 0; rep < 2; ++rep) {
      int p = t + (rep << 8);
      float v = accL[0][cc][p] + accL[1][cc][p] + accL[2][cc][p] + accL[3][cc][p];
      Hs[(size_t)cc * NPIX + (size_t)row * 512 + p] = v;
    }
  }
}

// sobel (zero pad) + alpha + F + mu.  mu layout: mu[p*6 + axis*3 + c]
__global__ void flow_kernel(const float* __restrict__ x, const float* __restrict__ Hs,
                            float* __restrict__ mu) {
  int p = blockIdx.x * 256 + threadIdx.x;
  int px = p >> 9, py = p & 511;
  float syH0 = 0.f, syH1 = 0.f, syH2 = 0.f;
  float sxH0 = 0.f, sxH1 = 0.f, sxH2 = 0.f;
  float syX = 0.f, sxX = 0.f;
#pragma unroll
  for (int di = -1; di <= 1; ++di) {
#pragma unroll
    for (int dj = -1; dj <= 1; ++dj) {
      if (di == 0 && dj == 0) continue;
      int xi = px + di, yj = py + dj;
      if ((unsigned)xi >= 512u || (unsigned)yj >= 512u) continue;  // zero pad
      float wy = (float)di * ((dj == 0) ? 2.f : 1.f);
      float wx = (float)dj * ((di == 0) ? 2.f : 1.f);
      int q = (xi << 9) | yj;
      float h0 = Hs[q], h1 = Hs[NPIX + q], h2 = Hs[2 * NPIX + q];
      syH0 += wy * h0; syH1 += wy * h1; syH2 += wy * h2;
      sxH0 += wx * h0; sxH1 += wx * h1; sxH2 += wx * h2;
      float xs = x[(size_t)q * 3 + 0] + x[(size_t)q * 3 + 1] + x[(size_t)q * 3 + 2];
      syX += wy * xs; sxX += wx * xs;
    }
  }
  float cxp = (float)px + 0.5f, cyp = (float)py + 0.5f;
  float* mup = mu + (size_t)p * 6;
  float syH[3] = {syH0, syH1, syH2};
  float sxH[3] = {sxH0, sxH1, sxH2};
#pragma unroll
  for (int c = 0; c < 3; ++c) {
    float xc = x[(size_t)p * 3 + c];
    float tt = xc * 0.5f;
    float alpha = fminf(tt * tt, 1.0f);
    float F0 = syH[c] * (1.f - alpha) - syX * alpha;
    float F1 = sxH[c] * (1.f - alpha) - sxX * alpha;
    float m0 = cxp + fminf(fmaxf(0.2f * F0, -1.05f), 1.05f);
    float m1 = cyp + fminf(fmaxf(0.2f * F1, -1.05f), 1.05f);
    mup[c]     = fminf(fmaxf(m0, 0.95f), 511.05f);
    mup[3 + c] = fminf(fmaxf(m1, 0.95f), 511.05f);
  }
}

// 25-offset reintegration gather
__global__ void reintegrate_kernel(const float* __restrict__ x, const float* __restrict__ mu,
                                   float* __restrict__ out) {
  int p = blockIdx.x * 256 + threadIdx.x;
  int px = p >> 9, py = p & 511;
  float cx = (float)px + 0.5f, cy = (float)py + 0.5f;
  float a0 = 0.f, a1 = 0.f, a2 = 0.f;
#pragma unroll
  for (int dx = -2; dx <= 2; ++dx) {
    int qx = (px - dx + 512) & 511;
#pragma unroll
    for (int dy = -2; dy <= 2; ++dy) {
      int qy = (py - dy + 512) & 511;
      int q = (qx << 9) | qy;
      const float* muq = mu + (size_t)q * 6;
      const float* gq = x + (size_t)q * 3;
      float w;
      w = fminf(fmaxf(1.45f - fabsf(cx - muq[0]), 0.f), 1.f) *
          fminf(fmaxf(1.45f - fabsf(cy - muq[3]), 0.f), 1.f);
      a0 += gq[0] * w;
      w = fminf(fmaxf(1.45f - fabsf(cx - muq[1]), 0.f), 1.f) *
          fminf(fmaxf(1.45f - fabsf(cy - muq[4]), 0.f), 1.f);
      a1 += gq[1] * w;
      w = fminf(fmaxf(1.45f - fabsf(cx - muq[2]), 0.f), 1.f) *
          fminf(fmaxf(1.45f - fabsf(cy - muq[5]), 0.f), 1.f);
      a2 += gq[2] * w;
    }
  }
  const float inv_area = 0.27700831f;  // 1/(4*0.95^2)
  out[(size_t)p * 3 + 0] = a0 * inv_area;
  out[(size_t)p * 3 + 1] = a1 * inv_area;
  out[(size_t)p * 3 + 2] = a2 * inv_area;
}

extern "C" void kernel_launch(void* const* d_in, const int* in_sizes, int n_in,
                              void* d_out, int out_size, void* d_ws, size_t ws_size,
                              hipStream_t stream) {
  const float* x    = (const float*)d_in[0];
  const float* Ks   = (const float*)d_in[1];
  const float* m    = (const float*)d_in[2];
  const float* s    = (const float*)d_in[3];
  const float* h    = (const float*)d_in[4];
  const float* w_c1 = (const float*)d_in[5];
  const int*   c0   = (const int*)d_in[6];
  float* out = (float*)d_out;

  char* ws = (char*)d_ws;
  size_t off = 0;
  float* sums    = (float*)(ws + off); off += 1024;
  float* partial = (float*)(ws + off); off += 1024 * 16 * 4;
  float*  Kt   = (float*)(ws + off);  off += (size_t)NKER * NPIX * 4;     // 15.7 MB
  float2* AxH  = (float2*)(ws + off); off += (size_t)3 * 512 * HW * 8;    // 3.2 MB
  float2* AkH  = (float2*)(ws + off); off += (size_t)NKER * 512 * HW * 8; // 16.2 MB
  float*  Hs   = (float*)(ws + off);  off += (size_t)3 * NPIX * 4;        // 3 MB
  float*  mu   = (float*)(ws + off);  off += (size_t)6 * NPIX * 4;        // 6 MB

  kprep<<<1024, 256, 0, stream>>>(Ks, Kt, partial);
  ksum_final<<<1, 256, 0, stream>>>(partial, sums);
  fft_rows_x<<<dim3(64, 3), 256, 0, stream>>>(x, AxH);
  fft_rows_k<<<dim3(64, NKER), 256, 0, stream>>>(Kt, sums, AkH);
  fused_cols<<<dim3(33, NKER), 512, 0, stream>>>(AkH, AxH, c0);
  irows_growth_combine<<<512, 256, 0, stream>>>(AkH, m, s, h, w_c1, Hs);
  flow_kernel<<<1024, 256, 0, stream>>>(x, Hs, mu);
  reintegrate_kernel<<<1024, 256, 0, stream>>>(x, mu, out);
}

// Round 8
// 147.737 us; speedup vs baseline: 1.1136x; 1.1136x over previous
//
#include <hip/hip_runtime.h>
#include <math.h>

#define NPIX 262144   // 512*512
#define NKER 15
#define PI_F 3.14159265358979323846f
#define HW 264        // half-plane row stride (float2): 257 used, padded to 8
#define CS 578        // wave scratch stride (float2): >= SK(511)=574
#define SK(n) ((n) + ((n) >> 3))   // skewed LDS index: <=4-way conflicts

__device__ __forceinline__ float2 cadd(float2 a, float2 b) { return make_float2(a.x + b.x, a.y + b.y); }
__device__ __forceinline__ float2 csub(float2 a, float2 b) { return make_float2(a.x - b.x, a.y - b.y); }
__device__ __forceinline__ float2 cmul(float2 a, float2 b) {
  return make_float2(a.x * b.x - a.y * b.y, a.x * b.y + a.y * b.x);
}

__device__ __forceinline__ void fft_roots(int lane, float2* w1, float2* wh) {
  float s, c;
  sincosf(-2.0f * PI_F * (float)lane / 512.0f, &s, &c);
  *w1 = make_float2(c, s);
  int h = lane & ~7;
  *wh = make_float2(__shfl(c, h, 64), __shfl(s, h, 64));
}

template <bool INV>
__device__ __forceinline__ void dft8(float2 a[8]) {
  const float R = 0.70710678118654752f;
  float2 t0 = cadd(a[0], a[4]), u0 = csub(a[0], a[4]);
  float2 t1 = cadd(a[1], a[5]), u1 = csub(a[1], a[5]);
  float2 t2 = cadd(a[2], a[6]), u2 = csub(a[2], a[6]);
  float2 t3 = cadd(a[3], a[7]), u3 = csub(a[3], a[7]);
  u1 = INV ? make_float2(R * (u1.x - u1.y), R * (u1.x + u1.y))
           : make_float2(R * (u1.x + u1.y), R * (u1.y - u1.x));
  u2 = INV ? make_float2(-u2.y, u2.x) : make_float2(u2.y, -u2.x);
  u3 = INV ? make_float2(-R * (u3.x + u3.y), R * (u3.x - u3.y))
           : make_float2(R * (u3.y - u3.x), -R * (u3.x + u3.y));
  float2 e0 = cadd(t0, t2), f0 = csub(t0, t2);
  float2 e1 = cadd(t1, t3), f1 = csub(t1, t3);
  f1 = INV ? make_float2(-f1.y, f1.x) : make_float2(f1.y, -f1.x);
  float2 g0 = cadd(u0, u2), h0 = csub(u0, u2);
  float2 g1 = cadd(u1, u3), h1 = csub(u1, u3);
  h1 = INV ? make_float2(-h1.y, h1.x) : make_float2(h1.y, -h1.x);
  a[0] = cadd(e0, e1); a[4] = csub(e0, e1);
  a[2] = cadd(f0, f1); a[6] = csub(f0, f1);
  a[1] = cadd(g0, g1); a[5] = csub(g0, g1);
  a[3] = cadd(h0, h1); a[7] = csub(h0, h1);
}

// 512-pt Stockham radix-8, one wave, 8 pts/thread, a[q] = point (lane+64q).
template <bool INV>
__device__ __forceinline__ void fft512_r8(float2 a[8], float2* buf, int lane,
                                          float2 w1, float2 wh) {
  float2 wa = INV ? make_float2(w1.x, -w1.y) : w1;
  float2 wb = INV ? make_float2(wh.x, -wh.y) : wh;
  dft8<INV>(a);
  {
    float2 tq = wa;
    a[1] = cmul(a[1], tq);
#pragma unroll
    for (int q = 2; q < 8; ++q) { tq = cmul(tq, wa); a[q] = cmul(a[q], tq); }
  }
#pragma unroll
  for (int q = 0; q < 8; ++q) buf[9 * lane + q] = a[q];
#pragma unroll
  for (int q = 0; q < 8; ++q) a[q] = buf[SK(lane + 64 * q)];
  dft8<INV>(a);
  {
    float2 tq = wb;
    a[1] = cmul(a[1], tq);
#pragma unroll
    for (int q = 2; q < 8; ++q) { tq = cmul(tq, wb); a[q] = cmul(a[q], tq); }
  }
  int h = lane & ~7;
  int b2 = 9 * h + (lane - h);
#pragma unroll
  for (int q = 0; q < 8; ++q) buf[b2 + 9 * q] = a[q];
#pragma unroll
  for (int q = 0; q < 8; ++q) a[q] = buf[SK(lane + 64 * q)];
  dft8<INV>(a);
}

// After packed FFT Z of (rowA + i rowB): write half-plane spectra of both rows.
__device__ __forceinline__ void split_store_halfplane(float2 a[8], float2* buf, int lane,
                                                      float2* d0, float2* d1) {
#pragma unroll
  for (int q = 0; q < 8; ++q) buf[SK(lane + 64 * q)] = a[q];
#pragma unroll
  for (int q = 0; q < 4; ++q) {
    int v = lane + 64 * q;
    int mir = (512 - v) & 511;
    float2 P = a[q];
    float2 Qc = buf[SK(mir)];
    float2 Q = make_float2(Qc.x, -Qc.y);
    d0[v] = make_float2(0.5f * (P.x + Q.x), 0.5f * (P.y + Q.y));
    d1[v] = make_float2(0.5f * (P.y - Q.y), -0.5f * (P.x - Q.x));
  }
  if (lane == 0) {
    float2 P = a[4];
    d0[256] = make_float2(P.x, 0.f);
    d1[256] = make_float2(P.y, 0.f);
  }
}

// ---- prep_rows: blocks 0..1023 = Ks transpose + partial sums;
//                 blocks 1024..1215 = R2C row FFT of x ----
__global__ void prep_rows(const float* __restrict__ Ks, const float* __restrict__ x,
                          float* __restrict__ Kt, float* __restrict__ partial,
                          float2* __restrict__ AxH) {
  __shared__ float wsum[4][16];
  __shared__ float2 scr[4][CS];
  int t = threadIdx.x, wave = t >> 6, lane = t & 63;
  if (blockIdx.x < 1024) {
    int p = blockIdx.x * 256 + t;
    const float* src = Ks + (size_t)p * NKER;
    float v[NKER];
#pragma unroll
    for (int k = 0; k < NKER; ++k) v[k] = src[k];
#pragma unroll
    for (int k = 0; k < NKER; ++k) Kt[(size_t)k * NPIX + p] = v[k];
#pragma unroll
    for (int k = 0; k < NKER; ++k) {
#pragma unroll
      for (int off = 32; off > 0; off >>= 1) v[k] += __shfl_down(v[k], off, 64);
    }
    if ((t & 63) == 0) {
#pragma unroll
      for (int k = 0; k < NKER; ++k) wsum[wave][k] = v[k];
    }
    __syncthreads();
    if (t < NKER)
      partial[blockIdx.x * 16 + t] = wsum[0][t] + wsum[1][t] + wsum[2][t] + wsum[3][t];
  } else {
    int b = blockIdx.x - 1024;         // 0..191
    int c = b >> 6;                    // channel 0..2
    int rp = (b & 63) * 4 + wave;      // 0..255
    int r0 = rp, r1 = rp + 256;
    float2 w1, wh;
    fft_roots(lane, &w1, &wh);
    float2 a[8];
#pragma unroll
    for (int q = 0; q < 8; ++q) {
      int y = lane + 64 * q;
      a[q] = make_float2(x[((size_t)r0 * 512 + y) * 3 + c],
                         x[((size_t)r1 * 512 + y) * 3 + c]);
    }
    fft512_r8<false>(a, &scr[wave][0], lane, w1, wh);
    float2* d0 = AxH + ((size_t)c * 512 + r0) * HW;
    float2* d1 = AxH + ((size_t)c * 512 + r1) * HW;
    split_store_halfplane(a, &scr[wave][0], lane, d0, d1);
  }
}

// ---- R2C row FFT of fftshift(Kt[k]) (UNSCALED; norm deferred to irows) ----
__global__ void fft_rows_k(const float* __restrict__ Kt, float2* __restrict__ AkH) {
  __shared__ float2 scr[4][CS];
  int t = threadIdx.x, wave = t >> 6, lane = t & 63;
  int rp = blockIdx.x * 4 + wave;
  int k = blockIdx.y;
  const float* s0 = Kt + (size_t)k * NPIX + (size_t)(rp + 256) * 512;
  const float* s1 = Kt + (size_t)k * NPIX + (size_t)rp * 512;
  float2 w1, wh;
  fft_roots(lane, &w1, &wh);
  float2 a[8];
#pragma unroll
  for (int q = 0; q < 8; ++q) {
    int ys = (lane + 64 * q + 256) & 511;
    a[q] = make_float2(s0[ys], s1[ys]);
  }
  fft512_r8<false>(a, &scr[wave][0], lane, w1, wh);
  float2* d0 = AkH + ((size_t)k * 512 + rp) * HW;
  float2* d1 = AkH + ((size_t)k * 512 + rp + 256) * HW;
  split_store_halfplane(a, &scr[wave][0], lane, d0, d1);
}

// ---- cols_x: forward column FFT of AxH -> XH (3 channels); block (33,0) does ksum ----
__global__ void cols_x(const float2* __restrict__ AxH, float2* __restrict__ XH,
                       const float* __restrict__ partial, float* __restrict__ sums) {
  __shared__ float2 buf[8 * CS];
  __shared__ float red[512];
  int t = threadIdx.x;
  if (blockIdx.x == 33) {
    if (blockIdx.y != 0) return;
    int k = t & 15, g = t >> 4;        // 32 groups x 16 slots
    float acc = 0.f;
    for (int b = g; b < 1024; b += 32) acc += partial[b * 16 + k];
    red[t] = acc;
    __syncthreads();
    if (t < 16) {
      float s = 0.f;
#pragma unroll
      for (int g2 = 0; g2 < 32; ++g2) s += red[g2 * 16 + t];
      sums[t] = s;
    }
    return;
  }
  int col0 = blockIdx.x * 8, ch = blockIdx.y;
  int c = t >> 6, lane = t & 63;
  float2 w1, wh;
  fft_roots(lane, &w1, &wh);
  const float2* bx = AxH + (size_t)ch * 512 * HW;
  float2* dst = XH + (size_t)ch * 512 * HW;
#pragma unroll
  for (int u = 0; u < 8; ++u) {
    int idx = (u << 9) + t;
    int row = idx >> 3, cc = idx & 7;
    buf[cc * CS + SK(row)] = bx[(size_t)row * HW + col0 + cc];
  }
  __syncthreads();
  float2 a[8];
#pragma unroll
  for (int q = 0; q < 8; ++q) a[q] = buf[c * CS + SK(lane + 64 * q)];
  fft512_r8<false>(a, &buf[c * CS], lane, w1, wh);
#pragma unroll
  for (int q = 0; q < 8; ++q) buf[c * CS + SK(lane + 64 * q)] = a[q];
  __syncthreads();
#pragma unroll
  for (int u = 0; u < 8; ++u) {
    int idx = (u << 9) + t;
    int row = idx >> 3, cc = idx & 7;
    dst[(size_t)row * HW + col0 + cc] = buf[cc * CS + SK(row)];
  }
}

// ---- fused column pass: colFFT(Ak), * XH (direct L2 reads), inverse colFFT ----
__global__ void fused_cols(float2* __restrict__ AkH, const float2* __restrict__ XH,
                           const int* __restrict__ c0) {
  __shared__ float2 buf[8 * CS];
  int t = threadIdx.x, col0 = blockIdx.x * 8, k = blockIdx.y;
  int c = t >> 6, lane = t & 63;
  float2 w1, wh;
  fft_roots(lane, &w1, &wh);
  const float2* bx = XH + (size_t)c0[k] * 512 * HW;
  float2* bk = AkH + (size_t)k * 512 * HW;
  int col = col0 + c;
  float2 xh[8];
#pragma unroll
  for (int q = 0; q < 8; ++q) xh[q] = bx[(size_t)(lane + 64 * q) * HW + col];
#pragma unroll
  for (int u = 0; u < 8; ++u) {
    int idx = (u << 9) + t;
    int row = idx >> 3, cc = idx & 7;
    buf[cc * CS + SK(row)] = bk[(size_t)row * HW + col0 + cc];
  }
  __syncthreads();
  float2 a[8];
#pragma unroll
  for (int q = 0; q < 8; ++q) a[q] = buf[c * CS + SK(lane + 64 * q)];
  fft512_r8<false>(a, &buf[c * CS], lane, w1, wh);
#pragma unroll
  for (int q = 0; q < 8; ++q) a[q] = cmul(a[q], xh[q]);
  fft512_r8<true>(a, &buf[c * CS], lane, w1, wh);
#pragma unroll
  for (int q = 0; q < 8; ++q) buf[c * CS + SK(lane + 64 * q)] = a[q];
  __syncthreads();
#pragma unroll
  for (int u = 0; u < 8; ++u) {
    int idx = (u << 9) + t;
    int row = idx >> 3, cc = idx & 7;
    bk[(size_t)row * HW + col0 + cc] = buf[cc * CS + SK(row)];
  }
}

// ---- C2R inverse row FFT + deferred norm + growth + combine -> Hs ----
__global__ void irows_growth_combine(const float2* __restrict__ AkH,
                                     const float* __restrict__ sums,
                                     const float* __restrict__ m, const float* __restrict__ s,
                                     const float* __restrict__ h, const float* __restrict__ w,
                                     float* __restrict__ Hs) {
  __shared__ float2 scr[4][CS];
  __shared__ float accL[4][3][512];
  __shared__ float mk[16], isk[16], hk[16], wk[16][3], sck[16];
  int t = threadIdx.x, wave = t >> 6, lane = t & 63;
  int row = blockIdx.x;
  if (t < NKER) {
    mk[t] = m[t]; isk[t] = 1.0f / s[t]; hk[t] = h[t];
    sck[t] = 1.0f / (sums[t] * 262144.0f);
    wk[t][0] = w[t * 3 + 0]; wk[t][1] = w[t * 3 + 1]; wk[t][2] = w[t * 3 + 2];
  }
  __syncthreads();
  float2 w1, wh;
  fft_roots(lane, &w1, &wh);
  float acc[3][8];
#pragma unroll
  for (int cc = 0; cc < 3; ++cc)
#pragma unroll
    for (int q = 0; q < 8; ++q) acc[cc][q] = 0.f;
  for (int si = 0; si < 2; ++si) {
    int slot = wave + 4 * si;
    int k1 = 2 * slot, k2 = 2 * slot + 1;
    bool dual = (k2 < NKER);
    const float2* p1 = AkH + ((size_t)k1 * 512 + row) * HW;
    const float2* p2 = AkH + ((size_t)(dual ? k2 : k1) * 512 + row) * HW;
    float2 a[8];
#pragma unroll
    for (int q = 0; q < 8; ++q) {
      int v = lane + 64 * q;
      if (v <= 256) {
        float2 A1 = p1[v];
        float2 A2 = dual ? p2[v] : make_float2(0.f, 0.f);
        a[q] = make_float2(A1.x - A2.y, A1.y + A2.x);          // A1 + i*A2
      } else {
        int mi = 512 - v;
        float2 A1 = p1[mi];
        float2 A2 = dual ? p2[mi] : make_float2(0.f, 0.f);
        a[q] = make_float2(A1.x + A2.y, -A1.y + A2.x);         // conj(A1) + i*conj(A2)
      }
    }
    fft512_r8<true>(a, &scr[wave][0], lane, w1, wh);
    float m1 = mk[k1], i1 = isk[k1], h1 = hk[k1], s1 = sck[k1];
    float w10 = wk[k1][0], w11 = wk[k1][1], w12 = wk[k1][2];
#pragma unroll
    for (int q = 0; q < 8; ++q) {
      float tt = (a[q].x * s1 - m1) * i1;
      float g = (expf(-0.5f * tt * tt) * 2.0f - 1.0f) * h1;
      acc[0][q] += g * w10; acc[1][q] += g * w11; acc[2][q] += g * w12;
    }
    if (dual) {
      float m2 = mk[k2], i2 = isk[k2], h2 = hk[k2], s2 = sck[k2];
      float w20 = wk[k2][0], w21 = wk[k2][1], w22 = wk[k2][2];
#pragma unroll
      for (int q = 0; q < 8; ++q) {
        float tt = (a[q].y * s2 - m2) * i2;
        float g = (expf(-0.5f * tt * tt) * 2.0f - 1.0f) * h2;
        acc[0][q] += g * w20; acc[1][q] += g * w21; acc[2][q] += g * w22;
      }
    }
  }
#pragma unroll
  for (int cc = 0; cc < 3; ++cc)
#pragma unroll
    for (int q = 0; q < 8; ++q) accL[wave][cc][lane + 64 * q] = acc[cc][q];
  __syncthreads();
#pragma unroll
  for (int cc = 0; cc < 3; ++cc) {
#pragma unroll
    for (int rep = 0; rep < 2; ++rep) {
      int p = t + (rep << 8);
      float v = accL[0][cc][p] + accL[1][cc][p] + accL[2][cc][p] + accL[3][cc][p];
      Hs[(size_t)cc * NPIX + (size_t)row * 512 + p] = v;
    }
  }
}

// ---- fused flow + reintegrate: 16x16 output tile, mu over 20x20 halo in LDS ----
__global__ void flow_reint(const float* __restrict__ x, const float* __restrict__ Hs,
                           float* __restrict__ out) {
  __shared__ float muT[20 * 20 * 6];
  __shared__ float xT[20 * 20 * 3];
  int ox = (blockIdx.x >> 5) << 4;   // 32x32 tiles of 16x16
  int oy = (blockIdx.x & 31) << 4;
  // phase 1: mu + x for the 20x20 halo (wrapped absolute pixels, zero-pad sobel)
  for (int i = threadIdx.x; i < 400; i += 256) {
    int hi = i / 20, hj = i % 20;
    int qx = (ox - 2 + hi) & 511, qy = (oy - 2 + hj) & 511;
    float syH0 = 0.f, syH1 = 0.f, syH2 = 0.f;
    float sxH0 = 0.f, sxH1 = 0.f, sxH2 = 0.f;
    float syX = 0.f, sxX = 0.f;
#pragma unroll
    for (int di = -1; di <= 1; ++di) {
#pragma unroll
      for (int dj = -1; dj <= 1; ++dj) {
        if (di == 0 && dj == 0) continue;
        int xi = qx + di, yj = qy + dj;
        if ((unsigned)xi >= 512u || (unsigned)yj >= 512u) continue;  // zero pad
        float wy = (float)di * ((dj == 0) ? 2.f : 1.f);
        float wx = (float)dj * ((di == 0) ? 2.f : 1.f);
        int q = (xi << 9) | yj;
        float h0 = Hs[q], h1 = Hs[NPIX + q], h2 = Hs[2 * NPIX + q];
        syH0 += wy * h0; syH1 += wy * h1; syH2 += wy * h2;
        sxH0 += wx * h0; sxH1 += wx * h1; sxH2 += wx * h2;
        float xs = x[(size_t)q * 3 + 0] + x[(size_t)q * 3 + 1] + x[(size_t)q * 3 + 2];
        syX += wy * xs; sxX += wx * xs;
      }
    }
    int qp = (qx << 9) | qy;
    float cxq = (float)qx + 0.5f, cyq = (float)qy + 0.5f;
    float syH[3] = {syH0, syH1, syH2};
    float sxH[3] = {sxH0, sxH1, sxH2};
    int b6 = i * 6, b3 = i * 3;
#pragma unroll
    for (int c = 0; c < 3; ++c) {
      float xc = x[(size_t)qp * 3 + c];
      xT[b3 + c] = xc;
      float tt = xc * 0.5f;
      float alpha = fminf(tt * tt, 1.0f);
      float F0 = syH[c] * (1.f - alpha) - syX * alpha;
      float F1 = sxH[c] * (1.f - alpha) - sxX * alpha;
      float m0 = cxq + fminf(fmaxf(0.2f * F0, -1.05f), 1.05f);
      float m1 = cyq + fminf(fmaxf(0.2f * F1, -1.05f), 1.05f);
      muT[b6 + c]     = fminf(fmaxf(m0, 0.95f), 511.05f);
      muT[b6 + 3 + c] = fminf(fmaxf(m1, 0.95f), 511.05f);
    }
  }
  __syncthreads();
  // phase 2: one output pixel per thread, 25-offset gather from LDS
  int o = threadIdx.x;
  int lx = o >> 4, ly = o & 15;
  int px_ = ox + lx, py_ = oy + ly;
  float cx = (float)px_ + 0.5f, cy = (float)py_ + 0.5f;
  float a0 = 0.f, a1 = 0.f, a2 = 0.f;
#pragma unroll
  for (int dx = -2; dx <= 2; ++dx) {
    int hi = lx + 2 - dx;
#pragma unroll
    for (int dy = -2; dy <= 2; ++dy) {
      int hj = ly + 2 - dy;
      int b6 = (hi * 20 + hj) * 6, b3 = (hi * 20 + hj) * 3;
      float wv;
      wv = fminf(fmaxf(1.45f - fabsf(cx - muT[b6 + 0]), 0.f), 1.f) *
           fminf(fmaxf(1.45f - fabsf(cy - muT[b6 + 3]), 0.f), 1.f);
      a0 += xT[b3 + 0] * wv;
      wv = fminf(fmaxf(1.45f - fabsf(cx - muT[b6 + 1]), 0.f), 1.f) *
           fminf(fmaxf(1.45f - fabsf(cy - muT[b6 + 4]), 0.f), 1.f);
      a1 += xT[b3 + 1] * wv;
      wv = fminf(fmaxf(1.45f - fabsf(cx - muT[b6 + 2]), 0.f), 1.f) *
           fminf(fmaxf(1.45f - fabsf(cy - muT[b6 + 5]), 0.f), 1.f);
      a2 += xT[b3 + 2] * wv;
    }
  }
  const float inv_area = 0.27700831f;  // 1/(4*0.95^2)
  size_t p = (size_t)((px_ << 9) | py_);
  out[p * 3 + 0] = a0 * inv_area;
  out[p * 3 + 1] = a1 * inv_area;
  out[p * 3 + 2] = a2 * inv_area;
}

extern "C" void kernel_launch(void* const* d_in, const int* in_sizes, int n_in,
                              void* d_out, int out_size, void* d_ws, size_t ws_size,
                              hipStream_t stream) {
  const float* x    = (const float*)d_in[0];
  const float* Ks   = (const float*)d_in[1];
  const float* m    = (const float*)d_in[2];
  const float* s    = (const float*)d_in[3];
  const float* h    = (const float*)d_in[4];
  const float* w_c1 = (const float*)d_in[5];
  const int*   c0   = (const int*)d_in[6];
  float* out = (float*)d_out;

  char* ws = (char*)d_ws;
  size_t off = 0;
  float* sums    = (float*)(ws + off); off += 1024;
  float* partial = (float*)(ws + off); off += 1024 * 16 * 4;
  float*  Kt   = (float*)(ws + off);  off += (size_t)NKER * NPIX * 4;     // 15.7 MB
  float2* AxH  = (float2*)(ws + off); off += (size_t)3 * 512 * HW * 8;    // 3.2 MB
  float2* XH   = (float2*)(ws + off); off += (size_t)3 * 512 * HW * 8;    // 3.2 MB
  float2* AkH  = (float2*)(ws + off); off += (size_t)NKER * 512 * HW * 8; // 16.2 MB
  float*  Hs   = (float*)(ws + off);  off += (size_t)3 * NPIX * 4;        // 3 MB

  prep_rows<<<1216, 256, 0, stream>>>(Ks, x, Kt, partial, AxH);
  fft_rows_k<<<dim3(64, NKER), 256, 0, stream>>>(Kt, AkH);
  cols_x<<<dim3(34, 3), 512, 0, stream>>>(AxH, XH, partial, sums);
  fused_cols<<<dim3(33, NKER), 512, 0, stream>>>(AkH, XH, c0);
  irows_growth_combine<<<512, 256, 0, stream>>>(AkH, sums, m, s, h, w_c1, Hs);
  flow_reint<<<1024, 256, 0, stream>>>(x, Hs, out);
}

// Round 10
// 135.445 us; speedup vs baseline: 1.2147x; 1.0908x over previous
//
#include <hip/hip_runtime.h>
#include <math.h>

#define NPIX 262144   // 512*512
#define NKER 15
#define PI_F 3.14159265358979323846f
#define HW 264        // half-plane row stride (float2): 257 used, padded to 8
#define NCOL 264      // processed half-plane columns (33 slabs x 8)
#define CS 578        // wave scratch stride (float2): >= SK(511)=574
#define SK(n) ((n) + ((n) >> 3))   // skewed LDS index: <=4-way conflicts

__device__ __forceinline__ float2 cadd(float2 a, float2 b) { return make_float2(a.x + b.x, a.y + b.y); }
__device__ __forceinline__ float2 csub(float2 a, float2 b) { return make_float2(a.x - b.x, a.y - b.y); }
__device__ __forceinline__ float2 cmul(float2 a, float2 b) {
  return make_float2(a.x * b.x - a.y * b.y, a.x * b.y + a.y * b.x);
}

__device__ __forceinline__ void fft_roots(int lane, float2* w1, float2* wh) {
  float s, c;
  sincosf(-2.0f * PI_F * (float)lane / 512.0f, &s, &c);
  *w1 = make_float2(c, s);
  int h = lane & ~7;
  *wh = make_float2(__shfl(c, h, 64), __shfl(s, h, 64));
}

template <bool INV>
__device__ __forceinline__ void dft8(float2 a[8]) {
  const float R = 0.70710678118654752f;
  float2 t0 = cadd(a[0], a[4]), u0 = csub(a[0], a[4]);
  float2 t1 = cadd(a[1], a[5]), u1 = csub(a[1], a[5]);
  float2 t2 = cadd(a[2], a[6]), u2 = csub(a[2], a[6]);
  float2 t3 = cadd(a[3], a[7]), u3 = csub(a[3], a[7]);
  u1 = INV ? make_float2(R * (u1.x - u1.y), R * (u1.x + u1.y))
           : make_float2(R * (u1.x + u1.y), R * (u1.y - u1.x));
  u2 = INV ? make_float2(-u2.y, u2.x) : make_float2(u2.y, -u2.x);
  u3 = INV ? make_float2(-R * (u3.x + u3.y), R * (u3.x - u3.y))
           : make_float2(R * (u3.y - u3.x), -R * (u3.x + u3.y));
  float2 e0 = cadd(t0, t2), f0 = csub(t0, t2);
  float2 e1 = cadd(t1, t3), f1 = csub(t1, t3);
  f1 = INV ? make_float2(-f1.y, f1.x) : make_float2(f1.y, -f1.x);
  float2 g0 = cadd(u0, u2), h0 = csub(u0, u2);
  float2 g1 = cadd(u1, u3), h1 = csub(u1, u3);
  h1 = INV ? make_float2(-h1.y, h1.x) : make_float2(h1.y, -h1.x);
  a[0] = cadd(e0, e1); a[4] = csub(e0, e1);
  a[2] = cadd(f0, f1); a[6] = csub(f0, f1);
  a[1] = cadd(g0, g1); a[5] = csub(g0, g1);
  a[3] = cadd(h0, h1); a[7] = csub(h0, h1);
}

// 512-pt Stockham radix-8, one wave, 8 pts/thread, a[q] = point (lane+64q).
template <bool INV>
__device__ __forceinline__ void fft512_r8(float2 a[8], float2* buf, int lane,
                                          float2 w1, float2 wh) {
  float2 wa = INV ? make_float2(w1.x, -w1.y) : w1;
  float2 wb = INV ? make_float2(wh.x, -wh.y) : wh;
  dft8<INV>(a);
  {
    float2 tq = wa;
    a[1] = cmul(a[1], tq);
#pragma unroll
    for (int q = 2; q < 8; ++q) { tq = cmul(tq, wa); a[q] = cmul(a[q], tq); }
  }
#pragma unroll
  for (int q = 0; q < 8; ++q) buf[9 * lane + q] = a[q];
#pragma unroll
  for (int q = 0; q < 8; ++q) a[q] = buf[SK(lane + 64 * q)];
  dft8<INV>(a);
  {
    float2 tq = wb;
    a[1] = cmul(a[1], tq);
#pragma unroll
    for (int q = 2; q < 8; ++q) { tq = cmul(tq, wb); a[q] = cmul(a[q], tq); }
  }
  int h = lane & ~7;
  int b2 = 9 * h + (lane - h);
#pragma unroll
  for (int q = 0; q < 8; ++q) buf[b2 + 9 * q] = a[q];
#pragma unroll
  for (int q = 0; q < 8; ++q) a[q] = buf[SK(lane + 64 * q)];
  dft8<INV>(a);
}

// After packed FFT Z of (seqA + i seqB): write half-plane spectra of both.
__device__ __forceinline__ void split_store_halfplane(float2 a[8], float2* buf, int lane,
                                                      float2* d0, float2* d1) {
#pragma unroll
  for (int q = 0; q < 8; ++q) buf[SK(lane + 64 * q)] = a[q];
#pragma unroll
  for (int q = 0; q < 4; ++q) {
    int v = lane + 64 * q;
    int mir = (512 - v) & 511;
    float2 P = a[q];
    float2 Qc = buf[SK(mir)];
    float2 Q = make_float2(Qc.x, -Qc.y);
    d0[v] = make_float2(0.5f * (P.x + Q.x), 0.5f * (P.y + Q.y));
    d1[v] = make_float2(0.5f * (P.y - Q.y), -0.5f * (P.x - Q.x));
  }
  if (lane == 0) {
    float2 P = a[4];
    d0[256] = make_float2(P.x, 0.f);
    d1[256] = make_float2(P.y, 0.f);
  }
}

// ---- rows_all ----
// blocks 0..511: output row b of shifted kernels — load Ks source row
//   (b+256)&511 (30 KB) coalesced into LDS; row-sums -> partial; 8 packed
//   R2C FFTs (k-pairs (2s,2s+1), plane 15 = dummy) -> AkH (UNSCALED).
// blocks 512..703: R2C row FFT of x (row-pairs (r, r+256)) -> AxH.
__global__ void rows_all(const float* __restrict__ Ks, const float* __restrict__ x,
                         float* __restrict__ partial, float2* __restrict__ AkH,
                         float2* __restrict__ AxH) {
  __shared__ float krow[512 * NKER];   // 30720 B
  __shared__ float2 scr[4][CS];        // 18496 B
  __shared__ float psum[480];
  int t = threadIdx.x, wave = t >> 6, lane = t & 63;
  float2 w1, wh;
  fft_roots(lane, &w1, &wh);
  if (blockIdx.x < 512) {
    int b = blockIdx.x;              // output row
    int rs = (b + 256) & 511;        // fftshift row source
    const float2* src = (const float2*)Ks + (size_t)rs * 3840;
    float2* kr2 = (float2*)krow;
#pragma unroll
    for (int i = 0; i < 15; ++i) kr2[t + 256 * i] = src[t + 256 * i];
    __syncthreads();
    // row sums: 15 k x 32 y-groups of 16  (grid-stride: 256 threads, 480 slots)
    for (int i = t; i < 480; i += 256) {
      int k = i >> 5, yg = i & 31;
      float s = 0.f;
      int base = yg * 16;
#pragma unroll
      for (int y = 0; y < 16; ++y) s += krow[(base + y) * NKER + k];
      psum[i] = s;
    }
    // packed k-pair FFTs: wave handles slots {wave, wave+4}
#pragma unroll
    for (int si = 0; si < 2; ++si) {
      int slot = wave + 4 * si;
      int k1 = 2 * slot, k2 = k1 + 1;     // k2==15 -> dummy plane
      float2 a[8];
#pragma unroll
      for (int q = 0; q < 8; ++q) {
        int ys = (lane + 64 * q + 256) & 511;   // fftshift col
        float re = krow[ys * NKER + k1];
        float im = (k2 < NKER) ? krow[ys * NKER + k2] : 0.f;
        a[q] = make_float2(re, im);
      }
      fft512_r8<false>(a, &scr[wave][0], lane, w1, wh);
      float2* d0 = AkH + ((size_t)k1 * 512 + b) * HW;
      float2* d1 = AkH + ((size_t)k2 * 512 + b) * HW;   // plane 15 = scratch
      split_store_halfplane(a, &scr[wave][0], lane, d0, d1);
    }
    __syncthreads();
    if (t < NKER) {
      float s = 0.f;
#pragma unroll
      for (int g = 0; g < 32; ++g) s += psum[(t << 5) + g];
      partial[b * 16 + t] = s;
    }
  } else {
    int b = blockIdx.x - 512;        // 0..191
    int c = b >> 6;                  // channel
    int rp = (b & 63) * 4 + wave;    // 0..255
    int r0 = rp, r1 = rp + 256;
    float2 a[8];
#pragma unroll
    for (int q = 0; q < 8; ++q) {
      int y = lane + 64 * q;
      a[q] = make_float2(x[((size_t)r0 * 512 + y) * 3 + c],
                         x[((size_t)r1 * 512 + y) * 3 + c]);
    }
    fft512_r8<false>(a, &scr[wave][0], lane, w1, wh);
    float2* d0 = AxH + ((size_t)c * 512 + r0) * HW;
    float2* d1 = AxH + ((size_t)c * 512 + r1) * HW;
    split_store_halfplane(a, &scr[wave][0], lane, d0, d1);
  }
}

// ---- mid_cols: blocks 0..98 = forward column FFT of AxH -> XHt[ch][col][row];
//                block 99 = ksum_final ----
__global__ void mid_cols(const float2* __restrict__ AxH, float2* __restrict__ XHt,
                         const float* __restrict__ partial, float* __restrict__ sums) {
  __shared__ float2 buf[8 * CS];
  __shared__ float red[512];
  int t = threadIdx.x;
  if (blockIdx.x == 99) {
    int k = t & 15, g = t >> 4;        // 32 groups x 16 slots
    float acc = 0.f;
    for (int b = g; b < 512; b += 32) acc += partial[b * 16 + k];
    red[t] = acc;
    __syncthreads();
    if (t < 16) {
      float s = 0.f;
#pragma unroll
      for (int g2 = 0; g2 < 32; ++g2) s += red[g2 * 16 + t];
      sums[t] = s;
    }
    return;
  }
  int ch = blockIdx.x / 33, slab = blockIdx.x % 33;
  int col0 = slab * 8;
  int c = t >> 6, lane = t & 63;
  float2 w1, wh;
  fft_roots(lane, &w1, &wh);
  const float2* bx = AxH + (size_t)ch * 512 * HW;
#pragma unroll
  for (int u = 0; u < 8; ++u) {
    int idx = (u << 9) + t;
    int row = idx >> 3, cc = idx & 7;
    buf[cc * CS + SK(row)] = bx[(size_t)row * HW + col0 + cc];
  }
  __syncthreads();
  float2 a[8];
#pragma unroll
  for (int q = 0; q < 8; ++q) a[q] = buf[c * CS + SK(lane + 64 * q)];
  fft512_r8<false>(a, &buf[c * CS], lane, w1, wh);
  // direct coalesced store: XHt[ch][col][row]
  float2* dst = XHt + ((size_t)ch * NCOL + col0 + c) * 512;
#pragma unroll
  for (int q = 0; q < 8; ++q) dst[lane + 64 * q] = a[q];
}

// ---- fused column pass: colFFT(Ak), * XHt (coalesced reads), inverse colFFT ----
__global__ void fused_cols(float2* __restrict__ AkH, const float2* __restrict__ XHt,
                           const int* __restrict__ c0) {
  __shared__ float2 buf[8 * CS];
  int t = threadIdx.x, col0 = blockIdx.x * 8, k = blockIdx.y;
  int c = t >> 6, lane = t & 63;
  float2 w1, wh;
  fft_roots(lane, &w1, &wh);
  float2* bk = AkH + (size_t)k * 512 * HW;
  const float2* xcol = XHt + ((size_t)c0[k] * NCOL + col0 + c) * 512;
  float2 xh[8];
#pragma unroll
  for (int q = 0; q < 8; ++q) xh[q] = xcol[lane + 64 * q];
#pragma unroll
  for (int u = 0; u < 8; ++u) {
    int idx = (u << 9) + t;
    int row = idx >> 3, cc = idx & 7;
    buf[cc * CS + SK(row)] = bk[(size_t)row * HW + col0 + cc];
  }
  __syncthreads();
  float2 a[8];
#pragma unroll
  for (int q = 0; q < 8; ++q) a[q] = buf[c * CS + SK(lane + 64 * q)];
  fft512_r8<false>(a, &buf[c * CS], lane, w1, wh);
#pragma unroll
  for (int q = 0; q < 8; ++q) a[q] = cmul(a[q], xh[q]);
  fft512_r8<true>(a, &buf[c * CS], lane, w1, wh);
#pragma unroll
  for (int q = 0; q < 8; ++q) buf[c * CS + SK(lane + 64 * q)] = a[q];
  __syncthreads();
#pragma unroll
  for (int u = 0; u < 8; ++u) {
    int idx = (u << 9) + t;
    int row = idx >> 3, cc = idx & 7;
    bk[(size_t)row * HW + col0 + cc] = buf[cc * CS + SK(row)];
  }
}

// ---- C2R inverse row FFT + deferred norm + growth + combine -> Hs ----
__global__ void irows_growth_combine(const float2* __restrict__ AkH,
                                     const float* __restrict__ sums,
                                     const float* __restrict__ m, const float* __restrict__ s,
                                     const float* __restrict__ h, const float* __restrict__ w,
                                     float* __restrict__ Hs) {
  __shared__ float2 scr[4][CS];
  __shared__ float accL[4][3][512];
  __shared__ float mk[16], isk[16], hk[16], wk[16][3], sck[16];
  int t = threadIdx.x, wave = t >> 6, lane = t & 63;
  int row = blockIdx.x;
  if (t < NKER) {
    mk[t] = m[t]; isk[t] = 1.0f / s[t]; hk[t] = h[t];
    sck[t] = 1.0f / (sums[t] * 262144.0f);
    wk[t][0] = w[t * 3 + 0]; wk[t][1] = w[t * 3 + 1]; wk[t][2] = w[t * 3 + 2];
  }
  __syncthreads();
  float2 w1, wh;
  fft_roots(lane, &w1, &wh);
  float acc[3][8];
#pragma unroll
  for (int cc = 0; cc < 3; ++cc)
#pragma unroll
    for (int q = 0; q < 8; ++q) acc[cc][q] = 0.f;
  for (int si = 0; si < 2; ++si) {
    int slot = wave + 4 * si;
    int k1 = 2 * slot, k2 = 2 * slot + 1;
    bool dual = (k2 < NKER);
    const float2* p1 = AkH + ((size_t)k1 * 512 + row) * HW;
    const float2* p2 = AkH + ((size_t)(dual ? k2 : k1) * 512 + row) * HW;
    float2 a[8];
#pragma unroll
    for (int q = 0; q < 8; ++q) {
      int v = lane + 64 * q;
      if (v <= 256) {
        float2 A1 = p1[v];
        float2 A2 = dual ? p2[v] : make_float2(0.f, 0.f);
        a[q] = make_float2(A1.x - A2.y, A1.y + A2.x);          // A1 + i*A2
      } else {
        int mi = 512 - v;
        float2 A1 = p1[mi];
        float2 A2 = dual ? p2[mi] : make_float2(0.f, 0.f);
        a[q] = make_float2(A1.x + A2.y, -A1.y + A2.x);         // conj(A1) + i*conj(A2)
      }
    }
    fft512_r8<true>(a, &scr[wave][0], lane, w1, wh);
    float m1 = mk[k1], i1 = isk[k1], h1 = hk[k1], s1 = sck[k1];
    float w10 = wk[k1][0], w11 = wk[k1][1], w12 = wk[k1][2];
#pragma unroll
    for (int q = 0; q < 8; ++q) {
      float tt = (a[q].x * s1 - m1) * i1;
      float g = (expf(-0.5f * tt * tt) * 2.0f - 1.0f) * h1;
      acc[0][q] += g * w10; acc[1][q] += g * w11; acc[2][q] += g * w12;
    }
    if (dual) {
      float m2 = mk[k2], i2 = isk[k2], h2 = hk[k2], s2 = sck[k2];
      float w20 = wk[k2][0], w21 = wk[k2][1], w22 = wk[k2][2];
#pragma unroll
      for (int q = 0; q < 8; ++q) {
        float tt = (a[q].y * s2 - m2) * i2;
        float g = (expf(-0.5f * tt * tt) * 2.0f - 1.0f) * h2;
        acc[0][q] += g * w20; acc[1][q] += g * w21; acc[2][q] += g * w22;
      }
    }
  }
#pragma unroll
  for (int cc = 0; cc < 3; ++cc)
#pragma unroll
    for (int q = 0; q < 8; ++q) accL[wave][cc][lane + 64 * q] = acc[cc][q];
  __syncthreads();
#pragma unroll
  for (int cc = 0; cc < 3; ++cc) {
#pragma unroll
    for (int rep = 0; rep < 2; ++rep) {
      int p = t + (rep << 8);
      float v = accL[0][cc][p] + accL[1][cc][p] + accL[2][cc][p] + accL[3][cc][p];
      Hs[(size_t)cc * NPIX + (size_t)row * 512 + p] = v;
    }
  }
}

// ---- fused flow + reintegrate: 16x16 output tile, mu over 20x20 halo in LDS ----
__global__ void flow_reint(const float* __restrict__ x, const float* __restrict__ Hs,
                           float* __restrict__ out) {
  __shared__ float muT[20 * 20 * 6];
  __shared__ float xT[20 * 20 * 3];
  int ox = (blockIdx.x >> 5) << 4;
  int oy = (blockIdx.x & 31) << 4;
  for (int i = threadIdx.x; i < 400; i += 256) {
    int hi = i / 20, hj = i % 20;
    int qx = (ox - 2 + hi) & 511, qy = (oy - 2 + hj) & 511;
    float syH0 = 0.f, syH1 = 0.f, syH2 = 0.f;
    float sxH0 = 0.f, sxH1 = 0.f, sxH2 = 0.f;
    float syX = 0.f, sxX = 0.f;
#pragma unroll
    for (int di = -1; di <= 1; ++di) {
#pragma unroll
      for (int dj = -1; dj <= 1; ++dj) {
        if (di == 0 && dj == 0) continue;
        int xi = qx + di, yj = qy + dj;
        if ((unsigned)xi >= 512u || (unsigned)yj >= 512u) continue;  // zero pad
        float wy = (float)di * ((dj == 0) ? 2.f : 1.f);
        float wx = (float)dj * ((di == 0) ? 2.f : 1.f);
        int q = (xi << 9) | yj;
        float h0 = Hs[q], h1 = Hs[NPIX + q], h2 = Hs[2 * NPIX + q];
        syH0 += wy * h0; syH1 += wy * h1; syH2 += wy * h2;
        sxH0 += wx * h0; sxH1 += wx * h1; sxH2 += wx * h2;
        float xs = x[(size_t)q * 3 + 0] + x[(size_t)q * 3 + 1] + x[(size_t)q * 3 + 2];
        syX += wy * xs; sxX += wx * xs;
      }
    }
    int qp = (qx << 9) | qy;
    float cxq = (float)qx + 0.5f, cyq = (float)qy + 0.5f;
    float syH[3] = {syH0, syH1, syH2};
    float sxH[3] = {sxH0, sxH1, sxH2};
    int b6 = i * 6, b3 = i * 3;
#pragma unroll
    for (int c = 0; c < 3; ++c) {
      float xc = x[(size_t)qp * 3 + c];
      xT[b3 + c] = xc;
      float tt = xc * 0.5f;
      float alpha = fminf(tt * tt, 1.0f);
      float F0 = syH[c] * (1.f - alpha) - syX * alpha;
      float F1 = sxH[c] * (1.f - alpha) - sxX * alpha;
      float m0 = cxq + fminf(fmaxf(0.2f * F0, -1.05f), 1.05f);
      float m1 = cyq + fminf(fmaxf(0.2f * F1, -1.05f), 1.05f);
      muT[b6 + c]     = fminf(fmaxf(m0, 0.95f), 511.05f);
      muT[b6 + 3 + c] = fminf(fmaxf(m1, 0.95f), 511.05f);
    }
  }
  __syncthreads();
  int o = threadIdx.x;
  int lx = o >> 4, ly = o & 15;
  int px_ = ox + lx, py_ = oy + ly;
  float cx = (float)px_ + 0.5f, cy = (float)py_ + 0.5f;
  float a0 = 0.f, a1 = 0.f, a2 = 0.f;
#pragma unroll
  for (int dx = -2; dx <= 2; ++dx) {
    int hi = lx + 2 - dx;
#pragma unroll
    for (int dy = -2; dy <= 2; ++dy) {
      int hj = ly + 2 - dy;
      int b6 = (hi * 20 + hj) * 6, b3 = (hi * 20 + hj) * 3;
      float wv;
      wv = fminf(fmaxf(1.45f - fabsf(cx - muT[b6 + 0]), 0.f), 1.f) *
           fminf(fmaxf(1.45f - fabsf(cy - muT[b6 + 3]), 0.f), 1.f);
      a0 += xT[b3 + 0] * wv;
      wv = fminf(fmaxf(1.45f - fabsf(cx - muT[b6 + 1]), 0.f), 1.f) *
           fminf(fmaxf(1.45f - fabsf(cy - muT[b6 + 4]), 0.f), 1.f);
      a1 += xT[b3 + 1] * wv;
      wv = fminf(fmaxf(1.45f - fabsf(cx - muT[b6 + 2]), 0.f), 1.f) *
           fminf(fmaxf(1.45f - fabsf(cy - muT[b6 + 5]), 0.f), 1.f);
      a2 += xT[b3 + 2] * wv;
    }
  }
  const float inv_area = 0.27700831f;  // 1/(4*0.95^2)
  size_t p = (size_t)((px_ << 9) | py_);
  out[p * 3 + 0] = a0 * inv_area;
  out[p * 3 + 1] = a1 * inv_area;
  out[p * 3 + 2] = a2 * inv_area;
}

extern "C" void kernel_launch(void* const* d_in, const int* in_sizes, int n_in,
                              void* d_out, int out_size, void* d_ws, size_t ws_size,
                              hipStream_t stream) {
  const float* x    = (const float*)d_in[0];
  const float* Ks   = (const float*)d_in[1];
  const float* m    = (const float*)d_in[2];
  const float* s    = (const float*)d_in[3];
  const float* h    = (const float*)d_in[4];
  const float* w_c1 = (const float*)d_in[5];
  const int*   c0   = (const int*)d_in[6];
  float* out = (float*)d_out;

  char* ws = (char*)d_ws;
  size_t off = 0;
  float* sums    = (float*)(ws + off); off += 1024;
  float* partial = (float*)(ws + off); off += 512 * 16 * 4;
  float2* AxH  = (float2*)(ws + off); off += (size_t)3 * 512 * HW * 8;    // 3.2 MB
  float2* XHt  = (float2*)(ws + off); off += (size_t)3 * NCOL * 512 * 8;  // 3.2 MB
  float2* AkH  = (float2*)(ws + off); off += (size_t)16 * 512 * HW * 8;   // 17.3 MB (plane 15 dummy)
  float*  Hs   = (float*)(ws + off);  off += (size_t)3 * NPIX * 4;        // 3 MB

  rows_all<<<704, 256, 0, stream>>>(Ks, x, partial, AkH, AxH);
  mid_cols<<<100, 512, 0, stream>>>(AxH, XHt, partial, sums);
  fused_cols<<<dim3(33, NKER), 512, 0, stream>>>(AkH, XHt, c0);
  irows_growth_combine<<<512, 256, 0, stream>>>(AkH, sums, m, s, h, w_c1, Hs);
  flow_reint<<<1024, 256, 0, stream>>>(x, Hs, out);
}

// Round 11
// 135.242 us; speedup vs baseline: 1.2165x; 1.0015x over previous
//
#include <hip/hip_runtime.h>
#include <math.h>

#define NPIX 262144   // 512*512
#define NKER 15
#define PI_F 3.14159265358979323846f
#define HW 264        // half-plane row stride (float2): 257 used, padded to 8
#define CS 578        // wave scratch stride (float2): >= SK(511)=574
#define SK(n) ((n) + ((n) >> 3))   // skewed LDS index: <=4-way conflicts

__device__ __forceinline__ float2 cadd(float2 a, float2 b) { return make_float2(a.x + b.x, a.y + b.y); }
__device__ __forceinline__ float2 csub(float2 a, float2 b) { return make_float2(a.x - b.x, a.y - b.y); }
__device__ __forceinline__ float2 cmul(float2 a, float2 b) {
  return make_float2(a.x * b.x - a.y * b.y, a.x * b.y + a.y * b.x);
}

__device__ __forceinline__ void fft_roots(int lane, float2* w1, float2* wh) {
  float s, c;
  sincosf(-2.0f * PI_F * (float)lane / 512.0f, &s, &c);
  *w1 = make_float2(c, s);
  int h = lane & ~7;
  *wh = make_float2(__shfl(c, h, 64), __shfl(s, h, 64));
}

template <bool INV>
__device__ __forceinline__ void dft8(float2 a[8]) {
  const float R = 0.70710678118654752f;
  float2 t0 = cadd(a[0], a[4]), u0 = csub(a[0], a[4]);
  float2 t1 = cadd(a[1], a[5]), u1 = csub(a[1], a[5]);
  float2 t2 = cadd(a[2], a[6]), u2 = csub(a[2], a[6]);
  float2 t3 = cadd(a[3], a[7]), u3 = csub(a[3], a[7]);
  u1 = INV ? make_float2(R * (u1.x - u1.y), R * (u1.x + u1.y))
           : make_float2(R * (u1.x + u1.y), R * (u1.y - u1.x));
  u2 = INV ? make_float2(-u2.y, u2.x) : make_float2(u2.y, -u2.x);
  u3 = INV ? make_float2(-R * (u3.x + u3.y), R * (u3.x - u3.y))
           : make_float2(R * (u3.y - u3.x), -R * (u3.x + u3.y));
  float2 e0 = cadd(t0, t2), f0 = csub(t0, t2);
  float2 e1 = cadd(t1, t3), f1 = csub(t1, t3);
  f1 = INV ? make_float2(-f1.y, f1.x) : make_float2(f1.y, -f1.x);
  float2 g0 = cadd(u0, u2), h0 = csub(u0, u2);
  float2 g1 = cadd(u1, u3), h1 = csub(u1, u3);
  h1 = INV ? make_float2(-h1.y, h1.x) : make_float2(h1.y, -h1.x);
  a[0] = cadd(e0, e1); a[4] = csub(e0, e1);
  a[2] = cadd(f0, f1); a[6] = csub(f0, f1);
  a[1] = cadd(g0, g1); a[5] = csub(g0, g1);
  a[3] = cadd(h0, h1); a[7] = csub(h0, h1);
}

// 512-pt Stockham radix-8, one wave, 8 pts/thread, a[q] = point (lane+64q).
template <bool INV>
__device__ __forceinline__ void fft512_r8(float2 a[8], float2* buf, int lane,
                                          float2 w1, float2 wh) {
  float2 wa = INV ? make_float2(w1.x, -w1.y) : w1;
  float2 wb = INV ? make_float2(wh.x, -wh.y) : wh;
  dft8<INV>(a);
  {
    float2 tq = wa;
    a[1] = cmul(a[1], tq);
#pragma unroll
    for (int q = 2; q < 8; ++q) { tq = cmul(tq, wa); a[q] = cmul(a[q], tq); }
  }
#pragma unroll
  for (int q = 0; q < 8; ++q) buf[9 * lane + q] = a[q];
#pragma unroll
  for (int q = 0; q < 8; ++q) a[q] = buf[SK(lane + 64 * q)];
  dft8<INV>(a);
  {
    float2 tq = wb;
    a[1] = cmul(a[1], tq);
#pragma unroll
    for (int q = 2; q < 8; ++q) { tq = cmul(tq, wb); a[q] = cmul(a[q], tq); }
  }
  int h = lane & ~7;
  int b2 = 9 * h + (lane - h);
#pragma unroll
  for (int q = 0; q < 8; ++q) buf[b2 + 9 * q] = a[q];
#pragma unroll
  for (int q = 0; q < 8; ++q) a[q] = buf[SK(lane + 64 * q)];
  dft8<INV>(a);
}

// After packed FFT Z of (seqA + i seqB): write half-plane spectra of both.
__device__ __forceinline__ void split_store_halfplane(float2 a[8], float2* buf, int lane,
                                                      float2* d0, float2* d1) {
#pragma unroll
  for (int q = 0; q < 8; ++q) buf[SK(lane + 64 * q)] = a[q];
#pragma unroll
  for (int q = 0; q < 4; ++q) {
    int v = lane + 64 * q;
    int mir = (512 - v) & 511;
    float2 P = a[q];
    float2 Qc = buf[SK(mir)];
    float2 Q = make_float2(Qc.x, -Qc.y);
    d0[v] = make_float2(0.5f * (P.x + Q.x), 0.5f * (P.y + Q.y));
    d1[v] = make_float2(0.5f * (P.y - Q.y), -0.5f * (P.x - Q.x));
  }
  if (lane == 0) {
    float2 P = a[4];
    d0[256] = make_float2(P.x, 0.f);
    d1[256] = make_float2(P.y, 0.f);
  }
}

// ---- rows_all (512 threads, 8 waves) ----
// blocks 0..511: output row b of shifted kernels — stage Ks source row
//   (b+256)&511 into LDS; row-sums -> partial; 8 waves each do ONE packed
//   k-pair FFT (slot=wave; plane 15 = dummy) -> AkH (UNSCALED).
// blocks 512..607: R2C row FFTs of x, 8 wave-jobs per block (3ch x 256 pairs).
__global__ void rows_all(const float* __restrict__ Ks, const float* __restrict__ x,
                         float* __restrict__ partial, float2* __restrict__ AkH,
                         float2* __restrict__ AxH) {
  __shared__ float krow[512 * NKER];   // 30720 B
  __shared__ float2 scr[8][CS];        // 36992 B
  __shared__ float psum[480];          // 1920 B
  int t = threadIdx.x, wave = t >> 6, lane = t & 63;
  float2 w1, wh;
  fft_roots(lane, &w1, &wh);
  if (blockIdx.x < 512) {
    int b = blockIdx.x;              // output row
    int rs = (b + 256) & 511;        // fftshift row source
    const float2* src = (const float2*)Ks + (size_t)rs * 3840;
    float2* kr2 = (float2*)krow;
    for (int i = t; i < 3840; i += 512) kr2[i] = src[i];
    __syncthreads();
    // row sums: 15 k x 32 y-groups of 16  (512 threads cover all 480 slots)
    if (t < 480) {
      int k = t >> 5, yg = t & 31;
      float s = 0.f;
      int base = yg * 16;
#pragma unroll
      for (int y = 0; y < 16; ++y) s += krow[(base + y) * NKER + k];
      psum[t] = s;
    }
    // one packed k-pair FFT per wave: slot = wave (0..7)
    {
      int k1 = 2 * wave, k2 = k1 + 1;     // k2==15 -> dummy plane
      float2 a[8];
#pragma unroll
      for (int q = 0; q < 8; ++q) {
        int ys = (lane + 64 * q + 256) & 511;   // fftshift col
        float re = krow[ys * NKER + k1];
        float im = (k2 < NKER) ? krow[ys * NKER + k2] : 0.f;
        a[q] = make_float2(re, im);
      }
      fft512_r8<false>(a, &scr[wave][0], lane, w1, wh);
      float2* d0 = AkH + ((size_t)k1 * 512 + b) * HW;
      float2* d1 = AkH + ((size_t)k2 * 512 + b) * HW;   // plane 15 = scratch
      split_store_halfplane(a, &scr[wave][0], lane, d0, d1);
    }
    __syncthreads();
    if (t < NKER) {
      float s = 0.f;
#pragma unroll
      for (int g = 0; g < 32; ++g) s += psum[(t << 5) + g];
      partial[b * 16 + t] = s;
    }
  } else {
    int job = (blockIdx.x - 512) * 8 + wave;   // 0..767
    int c = job >> 8;                // channel 0..2
    int rp = job & 255;              // row-pair 0..255
    int r0 = rp, r1 = rp + 256;
    float2 a[8];
#pragma unroll
    for (int q = 0; q < 8; ++q) {
      int y = lane + 64 * q;
      a[q] = make_float2(x[((size_t)r0 * 512 + y) * 3 + c],
                         x[((size_t)r1 * 512 + y) * 3 + c]);
    }
    fft512_r8<false>(a, &scr[wave][0], lane, w1, wh);
    float2* d0 = AxH + ((size_t)c * 512 + r0) * HW;
    float2* d1 = AxH + ((size_t)c * 512 + r1) * HW;
    split_store_halfplane(a, &scr[wave][0], lane, d0, d1);
  }
}

// ---- fused column pass (512 threads): stage AxH slab -> col FFT -> xh regs;
//      stage Ak slab -> fwd FFT -> *xh -> inv FFT -> store.
//      block (33, 0) = ksum_final; blocks (33, y>0) exit immediately. ----
__global__ void fused_cols(float2* __restrict__ AkH, const float2* __restrict__ AxH,
                           const int* __restrict__ c0, const float* __restrict__ partial,
                           float* __restrict__ sums) {
  __shared__ float2 buf[8 * CS];   // 36992 B
  __shared__ float red[512];
  int t = threadIdx.x;
  if (blockIdx.x == 33) {
    if (blockIdx.y != 0) return;
    int k = t & 15, g = t >> 4;        // 32 groups x 16 slots
    float acc = 0.f;
    for (int b = g; b < 512; b += 32) acc += partial[b * 16 + k];
    red[t] = acc;
    __syncthreads();
    if (t < 16) {
      float s = 0.f;
#pragma unroll
      for (int g2 = 0; g2 < 32; ++g2) s += red[g2 * 16 + t];
      sums[t] = s;
    }
    return;
  }
  int col0 = blockIdx.x * 8, k = blockIdx.y;
  int c = t >> 6, lane = t & 63;
  float2 w1, wh;
  fft_roots(lane, &w1, &wh);
  const float2* bx = AxH + (size_t)c0[k] * 512 * HW;
  float2* bk = AkH + (size_t)k * 512 * HW;
  // stage AxH slab (coalesced), col FFT -> xh in regs
#pragma unroll
  for (int u = 0; u < 8; ++u) {
    int idx = (u << 9) + t;
    int row = idx >> 3, cc = idx & 7;
    buf[cc * CS + SK(row)] = bx[(size_t)row * HW + col0 + cc];
  }
  __syncthreads();
  float2 xh[8];
#pragma unroll
  for (int q = 0; q < 8; ++q) xh[q] = buf[c * CS + SK(lane + 64 * q)];
  fft512_r8<false>(xh, &buf[c * CS], lane, w1, wh);
  __syncthreads();
  // stage Ak slab
#pragma unroll
  for (int u = 0; u < 8; ++u) {
    int idx = (u << 9) + t;
    int row = idx >> 3, cc = idx & 7;
    buf[cc * CS + SK(row)] = bk[(size_t)row * HW + col0 + cc];
  }
  __syncthreads();
  float2 a[8];
#pragma unroll
  for (int q = 0; q < 8; ++q) a[q] = buf[c * CS + SK(lane + 64 * q)];
  fft512_r8<false>(a, &buf[c * CS], lane, w1, wh);
#pragma unroll
  for (int q = 0; q < 8; ++q) a[q] = cmul(a[q], xh[q]);
  fft512_r8<true>(a, &buf[c * CS], lane, w1, wh);
#pragma unroll
  for (int q = 0; q < 8; ++q) buf[c * CS + SK(lane + 64 * q)] = a[q];
  __syncthreads();
#pragma unroll
  for (int u = 0; u < 8; ++u) {
    int idx = (u << 9) + t;
    int row = idx >> 3, cc = idx & 7;
    bk[(size_t)row * HW + col0 + cc] = buf[cc * CS + SK(row)];
  }
}

// ---- C2R inverse row FFT + deferred norm + growth + combine -> Hs ----
// 512 threads: 8 waves, slot = wave; two-step accL accumulation (4 planes).
__global__ void irows_growth_combine(const float2* __restrict__ AkH,
                                     const float* __restrict__ sums,
                                     const float* __restrict__ m, const float* __restrict__ s,
                                     const float* __restrict__ h, const float* __restrict__ w,
                                     float* __restrict__ Hs) {
  __shared__ float2 scr[8][CS];        // 36992 B
  __shared__ float accL[4][3][512];    // 24576 B
  __shared__ float mk[16], isk[16], hk[16], wk[16][3], sck[16];
  int t = threadIdx.x, wave = t >> 6, lane = t & 63;
  int row = blockIdx.x;
  if (t < NKER) {
    mk[t] = m[t]; isk[t] = 1.0f / s[t]; hk[t] = h[t];
    sck[t] = 1.0f / (sums[t] * 262144.0f);
    wk[t][0] = w[t * 3 + 0]; wk[t][1] = w[t * 3 + 1]; wk[t][2] = w[t * 3 + 2];
  }
  __syncthreads();
  float2 w1, wh;
  fft_roots(lane, &w1, &wh);
  float acc[3][8];
#pragma unroll
  for (int cc = 0; cc < 3; ++cc)
#pragma unroll
    for (int q = 0; q < 8; ++q) acc[cc][q] = 0.f;
  {
    int slot = wave;
    int k1 = 2 * slot, k2 = 2 * slot + 1;
    bool dual = (k2 < NKER);
    const float2* p1 = AkH + ((size_t)k1 * 512 + row) * HW;
    const float2* p2 = AkH + ((size_t)(dual ? k2 : k1) * 512 + row) * HW;
    float2 a[8];
#pragma unroll
    for (int q = 0; q < 8; ++q) {
      int v = lane + 64 * q;
      if (v <= 256) {
        float2 A1 = p1[v];
        float2 A2 = dual ? p2[v] : make_float2(0.f, 0.f);
        a[q] = make_float2(A1.x - A2.y, A1.y + A2.x);          // A1 + i*A2
      } else {
        int mi = 512 - v;
        float2 A1 = p1[mi];
        float2 A2 = dual ? p2[mi] : make_float2(0.f, 0.f);
        a[q] = make_float2(A1.x + A2.y, -A1.y + A2.x);         // conj(A1) + i*conj(A2)
      }
    }
    fft512_r8<true>(a, &scr[wave][0], lane, w1, wh);
    float m1 = mk[k1], i1 = isk[k1], h1 = hk[k1], s1 = sck[k1];
    float w10 = wk[k1][0], w11 = wk[k1][1], w12 = wk[k1][2];
#pragma unroll
    for (int q = 0; q < 8; ++q) {
      float tt = (a[q].x * s1 - m1) * i1;
      float g = (expf(-0.5f * tt * tt) * 2.0f - 1.0f) * h1;
      acc[0][q] += g * w10; acc[1][q] += g * w11; acc[2][q] += g * w12;
    }
    if (dual) {
      float m2 = mk[k2], i2 = isk[k2], h2 = hk[k2], s2 = sck[k2];
      float w20 = wk[k2][0], w21 = wk[k2][1], w22 = wk[k2][2];
#pragma unroll
      for (int q = 0; q < 8; ++q) {
        float tt = (a[q].y * s2 - m2) * i2;
        float g = (expf(-0.5f * tt * tt) * 2.0f - 1.0f) * h2;
        acc[0][q] += g * w20; acc[1][q] += g * w21; acc[2][q] += g * w22;
      }
    }
  }
  // two-step accumulation into 4 planes (waves 0-3 write, waves 4-7 add)
  if (wave < 4) {
#pragma unroll
    for (int cc = 0; cc < 3; ++cc)
#pragma unroll
      for (int q = 0; q < 8; ++q) accL[wave][cc][lane + 64 * q] = acc[cc][q];
  }
  __syncthreads();
  if (wave >= 4) {
#pragma unroll
    for (int cc = 0; cc < 3; ++cc)
#pragma unroll
      for (int q = 0; q < 8; ++q) accL[wave - 4][cc][lane + 64 * q] += acc[cc][q];
  }
  __syncthreads();
#pragma unroll
  for (int cc = 0; cc < 3; ++cc) {
    float v = accL[0][cc][t] + accL[1][cc][t] + accL[2][cc][t] + accL[3][cc][t];
    Hs[(size_t)cc * NPIX + (size_t)row * 512 + t] = v;
  }
}

// ---- fused flow + reintegrate: 16x16 output tile, mu over 20x20 halo in LDS ----
__global__ void flow_reint(const float* __restrict__ x, const float* __restrict__ Hs,
                           float* __restrict__ out) {
  __shared__ float muT[20 * 20 * 6];
  __shared__ float xT[20 * 20 * 3];
  int ox = (blockIdx.x >> 5) << 4;
  int oy = (blockIdx.x & 31) << 4;
  for (int i = threadIdx.x; i < 400; i += 256) {
    int hi = i / 20, hj = i % 20;
    int qx = (ox - 2 + hi) & 511, qy = (oy - 2 + hj) & 511;
    float syH0 = 0.f, syH1 = 0.f, syH2 = 0.f;
    float sxH0 = 0.f, sxH1 = 0.f, sxH2 = 0.f;
    float syX = 0.f, sxX = 0.f;
#pragma unroll
    for (int di = -1; di <= 1; ++di) {
#pragma unroll
      for (int dj = -1; dj <= 1; ++dj) {
        if (di == 0 && dj == 0) continue;
        int xi = qx + di, yj = qy + dj;
        if ((unsigned)xi >= 512u || (unsigned)yj >= 512u) continue;  // zero pad
        float wy = (float)di * ((dj == 0) ? 2.f : 1.f);
        float wx = (float)dj * ((di == 0) ? 2.f : 1.f);
        int q = (xi << 9) | yj;
        float h0 = Hs[q], h1 = Hs[NPIX + q], h2 = Hs[2 * NPIX + q];
        syH0 += wy * h0; syH1 += wy * h1; syH2 += wy * h2;
        sxH0 += wx * h0; sxH1 += wx * h1; sxH2 += wx * h2;
        float xs = x[(size_t)q * 3 + 0] + x[(size_t)q * 3 + 1] + x[(size_t)q * 3 + 2];
        syX += wy * xs; sxX += wx * xs;
      }
    }
    int qp = (qx << 9) | qy;
    float cxq = (float)qx + 0.5f, cyq = (float)qy + 0.5f;
    float syH[3] = {syH0, syH1, syH2};
    float sxH[3] = {sxH0, sxH1, sxH2};
    int b6 = i * 6, b3 = i * 3;
#pragma unroll
    for (int c = 0; c < 3; ++c) {
      float xc = x[(size_t)qp * 3 + c];
      xT[b3 + c] = xc;
      float tt = xc * 0.5f;
      float alpha = fminf(tt * tt, 1.0f);
      float F0 = syH[c] * (1.f - alpha) - syX * alpha;
      float F1 = sxH[c] * (1.f - alpha) - sxX * alpha;
      float m0 = cxq + fminf(fmaxf(0.2f * F0, -1.05f), 1.05f);
      float m1 = cyq + fminf(fmaxf(0.2f * F1, -1.05f), 1.05f);
      muT[b6 + c]     = fminf(fmaxf(m0, 0.95f), 511.05f);
      muT[b6 + 3 + c] = fminf(fmaxf(m1, 0.95f), 511.05f);
    }
  }
  __syncthreads();
  int o = threadIdx.x;
  int lx = o >> 4, ly = o & 15;
  int px_ = ox + lx, py_ = oy + ly;
  float cx = (float)px_ + 0.5f, cy = (float)py_ + 0.5f;
  float a0 = 0.f, a1 = 0.f, a2 = 0.f;
#pragma unroll
  for (int dx = -2; dx <= 2; ++dx) {
    int hi = lx + 2 - dx;
#pragma unroll
    for (int dy = -2; dy <= 2; ++dy) {
      int hj = ly + 2 - dy;
      int b6 = (hi * 20 + hj) * 6, b3 = (hi * 20 + hj) * 3;
      float wv;
      wv = fminf(fmaxf(1.45f - fabsf(cx - muT[b6 + 0]), 0.f), 1.f) *
           fminf(fmaxf(1.45f - fabsf(cy - muT[b6 + 3]), 0.f), 1.f);
      a0 += xT[b3 + 0] * wv;
      wv = fminf(fmaxf(1.45f - fabsf(cx - muT[b6 + 1]), 0.f), 1.f) *
           fminf(fmaxf(1.45f - fabsf(cy - muT[b6 + 4]), 0.f), 1.f);
      a1 += xT[b3 + 1] * wv;
      wv = fminf(fmaxf(1.45f - fabsf(cx - muT[b6 + 2]), 0.f), 1.f) *
           fminf(fmaxf(1.45f - fabsf(cy - muT[b6 + 5]), 0.f), 1.f);
      a2 += xT[b3 + 2] * wv;
    }
  }
  const float inv_area = 0.27700831f;  // 1/(4*0.95^2)
  size_t p = (size_t)((px_ << 9) | py_);
  out[p * 3 + 0] = a0 * inv_area;
  out[p * 3 + 1] = a1 * inv_area;
  out[p * 3 + 2] = a2 * inv_area;
}

extern "C" void kernel_launch(void* const* d_in, const int* in_sizes, int n_in,
                              void* d_out, int out_size, void* d_ws, size_t ws_size,
                              hipStream_t stream) {
  const float* x    = (const float*)d_in[0];
  const float* Ks   = (const float*)d_in[1];
  const float* m    = (const float*)d_in[2];
  const float* s    = (const float*)d_in[3];
  const float* h    = (const float*)d_in[4];
  const float* w_c1 = (const float*)d_in[5];
  const int*   c0   = (const int*)d_in[6];
  float* out = (float*)d_out;

  char* ws = (char*)d_ws;
  size_t off = 0;
  float* sums    = (float*)(ws + off); off += 1024;
  float* partial = (float*)(ws + off); off += 512 * 16 * 4;
  float2* AxH  = (float2*)(ws + off); off += (size_t)3 * 512 * HW * 8;    // 3.2 MB
  float2* AkH  = (float2*)(ws + off); off += (size_t)16 * 512 * HW * 8;   // 17.3 MB (plane 15 dummy)
  float*  Hs   = (float*)(ws + off);  off += (size_t)3 * NPIX * 4;        // 3 MB

  rows_all<<<608, 512, 0, stream>>>(Ks, x, partial, AkH, AxH);
  fused_cols<<<dim3(34, NKER), 512, 0, stream>>>(AkH, AxH, c0, partial, sums);
  irows_growth_combine<<<512, 512, 0, stream>>>(AkH, sums, m, s, h, w_c1, Hs);
  flow_reint<<<1024, 256, 0, stream>>>(x, Hs, out);
}